// Round 8
// baseline (111.778 us; speedup 1.0000x reference)
//
#include <hip/hip_runtime.h>

// inputs (256,128,64) f32, mask (256,128) i32, qparams (4,2,10) f32,
// W (4,256,10) f32, b (4,256) f32.
// out f32: outputs(256,128,256) ++ hx(128,256) ++ cx(128,256).
#define T_LEN 256
#define BATCH 128
#define NQ 10
#define HID 256
#define OUT_HX (T_LEN * BATCH * HID)
#define OUT_CX (OUT_HX + BATCH * HID)

#define KS  (-1.44269504089f)   // -log2(e): sigmoid scale
#define KT2 (-2.88539008178f)   // -2*log2(e): tanh scale

// ---------------- K1: circuit z precompute ----------------
// One thread per (t,g). Math identical to the validated analytic DP.
// Gate exp2-scale folded into z (sigmoid gates *KS, tanh gate *KT2).
// Layout zws[b][t][40] (n-major, g in float4 lanes): per-t row is 160B
// contiguous -> scanker's wave-uniform row loads are single-line L1 hits.
__global__ __launch_bounds__(256) void zker(
    const float* __restrict__ inputs,
    const float* __restrict__ qparams,
    float* __restrict__ zws)
{
  const int b   = blockIdx.x;
  const int tq  = blockIdx.y;
  const int tid = threadIdx.x;
  const int t   = tq * 64 + (tid >> 2);
  const int g   = tid & 3;

  const float sg = (g == 2) ? KT2 : KS;

  float th0[NQ], cth[NQ], sth[NQ];
#pragma unroll
  for (int k = 0; k < NQ; ++k) {
    th0[k]   = qparams[g * 2 * NQ + k];
    float t1 = qparams[g * 2 * NQ + NQ + k];
    sth[k] = __sinf(t1);
    cth[k] = __cosf(t1);
  }
  float cphi[NQ], sphi[NQ];
  const float* xp = inputs + (t * BATCH + b) * 64;
#pragma unroll
  for (int k = 0; k < NQ; ++k) {
    float ang = xp[k] + th0[k];
    sphi[k] = __sinf(ang);
    cphi[k] = __cosf(ang);
  }
  float* zout = zws + (b * T_LEN + t) * 40 + g;   // + n*4 per qubit
#pragma unroll
  for (int w = 0; w < NQ; ++w) {
    float vI, vZ, vY, vX; int js;
    if (w == NQ - 1) { vI = 0.f; vZ = cth[NQ-1]; vY = sth[NQ-1]; vX = 0.f; js = NQ - 2; }
    else             { vI = 1.f; vZ = 0.f; vY = 0.f; vX = 0.f; js = w; }
#pragma unroll
    for (int j = js; j >= 0; --j) {
      float nI = cth[j] * (cphi[j+1] * vZ - sphi[j+1] * vY);
      float nZ = cth[j] * vI;
      float nY = sth[j] * vX;
      float nX = -sth[j] * (sphi[j+1] * vZ + cphi[j+1] * vY);
      vI = nI; vZ = nZ; vY = nY; vX = nX;
    }
    zout[w * 4] = (vI + cphi[0] * vZ - sphi[0] * vY) * sg;
  }
}

// ---------------- K2: lane = h, chunked affine scan ----------------
// R2-R7 post-mortem: the ~40us plateau was never the scan - it was the gate
// phase re-issuing 160 scalar W loads per wave per round (lane=t made W
// wave-uniform -> SMEM churn + lgkm stalls). This version: lane = h, so W
// lives in 40 VGPRs loaded ONCE; z[t] is wave-uniform (one 160B row/step,
// L1 broadcast). t handled by chunked affine scan: 8 waves x 32-t chunks;
// pass 1 composes (A,W) per chunk sequentially in-register (pure VALU, no
// cross-lane); LDS combine gives carry-in; pass 2 recomputes gates, runs the
// exact sequential recurrence, stores h coalesced. 2 barriers total.
__global__ __launch_bounds__(512, 4) void scanker(
    const float* __restrict__ zws,
    const int*  __restrict__ mask,
    const float* __restrict__ W,
    const float* __restrict__ bias,
    float* __restrict__ out)
{
  const int b    = blockIdx.x;      // 0..127
  const int h0   = blockIdx.y * 64; // h-group base (4 groups)
  const int tid  = threadIdx.x;     // 0..511
  const int lane = tid & 63;
  const int wavu = __builtin_amdgcn_readfirstlane(tid >> 6);  // t-chunk id
  const int h    = h0 + lane;

  __shared__ float mk[T_LEN];       // 1024 B
  __shared__ float cA[8][64];       // 2048 B  chunk composite A
  __shared__ float cW[8][64];       // 2048 B  chunk composite W

  for (int t = tid; t < T_LEN; t += 512) mk[t] = (float)mask[t * BATCH + b];

  // per-lane weights: loaded once into VGPRs (the whole point)
  float Wf[NQ], Wi[NQ], Wg[NQ], Wo[NQ];
#pragma unroll
  for (int n = 0; n < NQ; ++n) {
    Wf[n] = W[(0 * HID + h) * NQ + n];
    Wi[n] = W[(1 * HID + h) * NQ + n];
    Wg[n] = W[(2 * HID + h) * NQ + n];
    Wo[n] = W[(3 * HID + h) * NQ + n];
  }
  const float bf = bias[0 * HID + h] * KS;
  const float bi = bias[1 * HID + h] * KS;
  const float bg = bias[2 * HID + h] * KT2;
  const float bo = bias[3 * HID + h] * KS;

  const float* zb = zws + b * T_LEN * 40;
  __syncthreads();   // mk ready

  // ---- pass 1: compose chunk affine op (A, Wc) over t = wavu*32 + k ----
  float A = 1.f, Wc = 0.f;
  for (int k = 0; k < 32; ++k) {
    const int t = wavu * 32 + k;                    // wave-uniform
    const float4* zrow = (const float4*)(zb + t * 40);
    float4 z4[NQ];
#pragma unroll
    for (int n = 0; n < NQ; ++n) z4[n] = zrow[n];   // uniform row, L1 bcast
    const float m = mk[t];
    const float onem = 1.f - m;
    float p0 = bf, p1 = bi, p2 = bg;
#pragma unroll
    for (int n = 0; n < NQ; ++n) {
      p0 = fmaf(z4[n].x, Wf[n], p0);
      p1 = fmaf(z4[n].y, Wi[n], p1);
      p2 = fmaf(z4[n].z, Wg[n], p2);
    }
    const float uf = __builtin_amdgcn_rcpf(1.f + __builtin_amdgcn_exp2f(p0));
    const float ui = __builtin_amdgcn_rcpf(1.f + __builtin_amdgcn_exp2f(p1));
    const float ug = __builtin_amdgcn_rcpf(1.f + __builtin_amdgcn_exp2f(p2));
    const float a  = fmaf(m, uf, onem);             // decay a_t
    const float wt = m * ui * fmaf(2.f, ug, -1.f);  // input w_t (m*m==m)
    Wc = fmaf(a, Wc, wt);
    A  = a * A;
  }
  cA[wavu][lane] = A;
  cW[wavu][lane] = Wc;
  __syncthreads();

  // ---- carry-in for this chunk: compose preceding segments ----
  float c = 0.f;
  for (int k = 0; k < wavu; ++k)                    // wave-uniform trip count
    c = fmaf(cA[k][lane], c, cW[k][lane]);

  // ---- pass 2: exact sequential recurrence within chunk + store ----
  float hv = 0.f;
  for (int k = 0; k < 32; ++k) {
    const int t = wavu * 32 + k;
    const float4* zrow = (const float4*)(zb + t * 40);
    float4 z4[NQ];
#pragma unroll
    for (int n = 0; n < NQ; ++n) z4[n] = zrow[n];
    const float m = mk[t];
    const float onem = 1.f - m;
    float p0 = bf, p1 = bi, p2 = bg, p3 = bo;
#pragma unroll
    for (int n = 0; n < NQ; ++n) {
      p0 = fmaf(z4[n].x, Wf[n], p0);
      p1 = fmaf(z4[n].y, Wi[n], p1);
      p2 = fmaf(z4[n].z, Wg[n], p2);
      p3 = fmaf(z4[n].w, Wo[n], p3);
    }
    const float uf = __builtin_amdgcn_rcpf(1.f + __builtin_amdgcn_exp2f(p0));
    const float ui = __builtin_amdgcn_rcpf(1.f + __builtin_amdgcn_exp2f(p1));
    const float ug = __builtin_amdgcn_rcpf(1.f + __builtin_amdgcn_exp2f(p2));
    const float uo = __builtin_amdgcn_rcpf(1.f + __builtin_amdgcn_exp2f(p3));
    const float a  = fmaf(m, uf, onem);
    const float wt = m * ui * fmaf(2.f, ug, -1.f);
    const float om = fmaf(m, uo, onem);
    c = fmaf(a, c, wt);
    const float ec = __builtin_amdgcn_exp2f(c * KT2);
    const float tc = fmaf(2.f, __builtin_amdgcn_rcpf(1.f + ec), -1.f);
    hv = om * tc;
    out[t * (BATCH * HID) + b * HID + h] = hv;      // 256B coalesced per t
  }
  if (wavu == 7) {
    out[OUT_HX + b * HID + h] = hv;
    out[OUT_CX + b * HID + h] = c;
  }
}

extern "C" void kernel_launch(void* const* d_in, const int* in_sizes, int n_in,
                              void* d_out, int out_size, void* d_ws, size_t ws_size,
                              hipStream_t stream)
{
  // identify arrays by unique element counts (order-proof)
  int ii = 0, im = 1, iq = 2, iw = 3, ib = 4;
  for (int i = 0; i < n_in; ++i) {
    switch (in_sizes[i]) {
      case 2097152: ii = i; break;   // inputs (256,128,64)
      case 32768:   im = i; break;   // mask (256,128)
      case 80:      iq = i; break;   // qparams (4,2,10)
      case 10240:   iw = i; break;   // W (4,256,10)
      case 1024:    ib = i; break;   // b (4,256)
      default: break;
    }
  }
  const float* inputs  = (const float*)d_in[ii];
  const int*   mask    = (const int*)d_in[im];
  const float* qparams = (const float*)d_in[iq];
  const float* W       = (const float*)d_in[iw];
  const float* bias    = (const float*)d_in[ib];
  float*       out     = (float*)d_out;
  float*       zws     = (float*)d_ws;   // needs 128*256*40*4 = 5.25 MB

  zker<<<dim3(BATCH, 4), dim3(256), 0, stream>>>(inputs, qparams, zws);
  scanker<<<dim3(BATCH, 4), dim3(512), 0, stream>>>(zws, mask, W, bias, out);
}